// Round 2
// baseline (1429.088 us; speedup 1.0000x reference)
//
#include <hip/hip_runtime.h>
#include <math.h>

#define T_LEN 512
#define H_DIM 50

__device__ __forceinline__ float sigmoid_f(float v) {
    return 1.0f / (1.0f + __expf(-v));
}
// tanh via fast exp; saturates correctly for large |v| (exp->inf/0).
__device__ __forceinline__ float tanh_f(float v) {
    return 1.0f - 2.0f / (__expf(2.0f * v) + 1.0f);
}

// One block = one wave = one batch element for the entire T=512 recurrence.
// Lane u (< 50) owns hidden unit u: holds W_hh rows {u, 50+u, 100+u, 150+u}
// (i,f,g,o) in 200 persistent VGPRs, plus c[u] in a register. h is shared via
// double-buffered LDS (broadcast ds_read_b128). Lanes 50..63 compute a
// harmless duplicate of unit 49 and never write.
// __launch_bounds__(64, 1): unified VGPR budget 512 -> ~230 arch VGPRs fit
// with NO AGPR spill (at (64,2) the compiler split 128 arch + ~100 acc and
// every weight use paid an extra v_accvgpr_read -> 3x VALU inflation).
__global__ __launch_bounds__(64, 1) void lstm_fused(
    const float* __restrict__ x,
    const float* __restrict__ W_ih,
    const float* __restrict__ W_hh,
    const float* __restrict__ b_ih,
    const float* __restrict__ b_hh,
    const float* __restrict__ W_fc,
    const float* __restrict__ b_fc,
    float* __restrict__ out)
{
    const int b = blockIdx.x;
    const int u = threadIdx.x;               // 0..63; active unit if u < 50
    const bool act = (u < H_DIM);
    const int uc = act ? u : (H_DIM - 1);    // clamp: inactive lanes mirror unit 49

    __shared__ float xs[T_LEN];
    __shared__ float hs[2][52];              // row stride 52 floats (16B-aligned)

    // Stage the whole input sequence for this batch element (I=1): 512 floats.
    {
        const float4* xb4 = reinterpret_cast<const float4*>(x + (size_t)b * T_LEN);
        float4* xs4 = reinterpret_cast<float4*>(xs);
        xs4[u]      = xb4[u];
        xs4[u + 64] = xb4[u + 64];
    }
    if (u < 52) { hs[0][u] = 0.0f; hs[1][u] = 0.0f; }

    // One-time per-thread weight load: 4 rows x 50 = 200 VGPRs.
    float W[4][H_DIM];
    float wih[4], bias[4];
    #pragma unroll
    for (int g = 0; g < 4; ++g) {
        const int row = g * H_DIM + uc;      // in [0,200)
        wih[g]  = W_ih[row];                 // W_ih is [200][1]
        bias[g] = b_ih[row] + b_hh[row];
        const float2* wr = reinterpret_cast<const float2*>(W_hh + (size_t)row * H_DIM);
        #pragma unroll
        for (int j2 = 0; j2 < H_DIM / 2; ++j2) {   // 25 x float2 (rows are 200B apart)
            const float2 w2 = wr[j2];
            W[g][2 * j2]     = w2.x;
            W[g][2 * j2 + 1] = w2.y;
        }
    }

    float c = 0.0f;
    __syncthreads();

    #pragma unroll 2
    for (int t = 0; t < T_LEN; ++t) {
        const int cur = t & 1;
        const float xv = xs[t];

        float a[4];
        #pragma unroll
        for (int g = 0; g < 4; ++g) a[g] = __fmaf_rn(xv, wih[g], bias[g]);

        // gates += W_hh[row] . h   (h broadcast from LDS: 12x b128 + 1x b64)
        #pragma unroll
        for (int q = 0; q < 12; ++q) {
            const float4 h4 = *reinterpret_cast<const float4*>(&hs[cur][4 * q]);
            #pragma unroll
            for (int g = 0; g < 4; ++g) {
                a[g] = __fmaf_rn(W[g][4 * q + 0], h4.x, a[g]);
                a[g] = __fmaf_rn(W[g][4 * q + 1], h4.y, a[g]);
                a[g] = __fmaf_rn(W[g][4 * q + 2], h4.z, a[g]);
                a[g] = __fmaf_rn(W[g][4 * q + 3], h4.w, a[g]);
            }
        }
        {
            const float2 h2 = *reinterpret_cast<const float2*>(&hs[cur][48]);
            #pragma unroll
            for (int g = 0; g < 4; ++g) {
                a[g] = __fmaf_rn(W[g][48], h2.x, a[g]);
                a[g] = __fmaf_rn(W[g][49], h2.y, a[g]);
            }
        }

        // LSTM cell update (torch gate order i,f,g,o)
        const float ig = sigmoid_f(a[0]);
        const float fg = sigmoid_f(a[1]);
        const float gg = tanh_f(a[2]);
        const float og = sigmoid_f(a[3]);
        c = __fmaf_rn(fg, c, ig * gg);
        const float hv = og * tanh_f(c);

        if (act) hs[cur ^ 1][u] = hv;
        __syncthreads();   // 1-wave block: compiles to waitcnt + cheap barrier
    }

    // Final h is in hs[0] (t=511 wrote buffer 0). out[b] = h . W_fc + b_fc
    float part = 0.0f;
    if (act) part = hs[0][u] * W_fc[u];
    #pragma unroll
    for (int off = 32; off > 0; off >>= 1) part += __shfl_down(part, off);
    if (u == 0) out[b] = part + b_fc[0];
}

extern "C" void kernel_launch(void* const* d_in, const int* in_sizes, int n_in,
                              void* d_out, int out_size, void* d_ws, size_t ws_size,
                              hipStream_t stream) {
    const float* x    = (const float*)d_in[0];
    const float* W_ih = (const float*)d_in[1];
    const float* W_hh = (const float*)d_in[2];
    const float* b_ih = (const float*)d_in[3];
    const float* b_hh = (const float*)d_in[4];
    const float* W_fc = (const float*)d_in[5];
    const float* b_fc = (const float*)d_in[6];
    float* out = (float*)d_out;

    const int B = in_sizes[0] / T_LEN;   // 4096
    lstm_fused<<<dim3(B), dim3(64), 0, stream>>>(x, W_ih, W_hh, b_ih, b_hh, W_fc, b_fc, out);
}

// Round 3
// 1089.253 us; speedup vs baseline: 1.3120x; 1.3120x over previous
//
#include <hip/hip_runtime.h>
#include <math.h>

#define T_LEN 512
#define H_DIM 50

__device__ __forceinline__ float sigmoid_f(float v) {
    return 1.0f / (1.0f + __expf(-v));
}
// tanh via fast exp; saturates correctly for large |v| (exp->inf/0).
__device__ __forceinline__ float tanh_f(float v) {
    return 1.0f - 2.0f / (__expf(2.0f * v) + 1.0f);
}

// Block = 256 threads = 4 waves = ONE batch element for the whole T=512
// recurrence. Wave w owns gate w (0=i,1=f,2=g,3=o); lane u owns unit u's row
// of that gate: W_hh row w*50+u -> 50 persistent VGPRs/thread (no spill risk;
// rounds 1-2 showed the compiler refuses 200-float residency). h is broadcast
// from double-buffered LDS. Wave 0 is the cell-update leader (holds c,h).
// Lanes 50..63 compute a harmless duplicate of unit 49 and never write state.
__global__ __launch_bounds__(256, 4) void lstm_fused(
    const float* __restrict__ x,
    const float* __restrict__ W_ih,
    const float* __restrict__ W_hh,
    const float* __restrict__ b_ih,
    const float* __restrict__ b_hh,
    const float* __restrict__ W_fc,
    const float* __restrict__ b_fc,
    float* __restrict__ out)
{
    const int b   = blockIdx.x;
    const int tid = threadIdx.x;
    const int w   = tid >> 6;               // gate index 0..3
    const int u   = tid & 63;               // unit lane 0..63
    const bool act = (u < H_DIM);
    const int uc  = act ? u : (H_DIM - 1);  // clamp inactive lanes to unit 49

    __shared__ float  xs[T_LEN];            // this batch element's inputs (I=1)
    __shared__ float4 hs4[2][13];           // h double buffer, 52 floats each
    __shared__ float  gl[4][64];            // activated gate values per step

    // Stage x: 512 floats, 256 threads x float2 (coalesced, 8B/lane).
    {
        const float2* xb2 = reinterpret_cast<const float2*>(x + (size_t)b * T_LEN);
        reinterpret_cast<float2*>(xs)[tid] = xb2[tid];
    }
    if (tid < 26) reinterpret_cast<float4*>(hs4)[tid] = float4{0.f, 0.f, 0.f, 0.f};

    // One-time weight load: row w*50+uc of W_hh (50 floats; rows are 200B apart).
    float W[H_DIM];
    const int row   = w * H_DIM + uc;       // in [0,200)
    const float wih  = W_ih[row];           // W_ih is [200][1]
    const float bias = b_ih[row] + b_hh[row];
    {
        const float2* wr = reinterpret_cast<const float2*>(W_hh + (size_t)row * H_DIM);
        #pragma unroll
        for (int j = 0; j < H_DIM / 2; ++j) {
            const float2 t2 = wr[j];
            W[2 * j]     = t2.x;
            W[2 * j + 1] = t2.y;
        }
    }

    float c = 0.0f, h = 0.0f;               // live only on wave 0
    __syncthreads();

    #pragma unroll 2
    for (int t = 0; t < T_LEN; ++t) {
        const int cur = t & 1;
        const float xv = xs[t];             // broadcast

        // a = bias + wih*x_t + W_row . h   (4 independent FMA chains)
        float a0 = __fmaf_rn(xv, wih, bias), a1 = 0.f, a2 = 0.f, a3 = 0.f;
        const float4* hb = hs4[cur];
        #pragma unroll
        for (int q = 0; q < 12; ++q) {
            const float4 h4 = hb[q];        // broadcast ds_read_b128
            a0 = __fmaf_rn(W[4 * q + 0], h4.x, a0);
            a1 = __fmaf_rn(W[4 * q + 1], h4.y, a1);
            a2 = __fmaf_rn(W[4 * q + 2], h4.z, a2);
            a3 = __fmaf_rn(W[4 * q + 3], h4.w, a3);
        }
        {
            const float2 h2 = *reinterpret_cast<const float2*>(&hb[12]);
            a0 = __fmaf_rn(W[48], h2.x, a0);
            a1 = __fmaf_rn(W[49], h2.y, a1);
        }
        const float a = (a0 + a2) + (a1 + a3);

        // Gate-specific activation (uniform branch per wave).
        const float v = (w == 2) ? tanh_f(a) : sigmoid_f(a);
        gl[w][u] = v;
        __syncthreads();

        // Leader wave updates the cell and publishes h.
        if (w == 0) {
            const float gf = gl[1][u];
            const float gg = gl[2][u];
            const float go = gl[3][u];
            c = __fmaf_rn(gf, c, v * gg);   // v = sigmoid(i) on wave 0
            h = go * tanh_f(c);
            if (act) reinterpret_cast<float*>(hs4[cur ^ 1])[u] = h;
        }
        __syncthreads();
    }

    // out[b] = h . W_fc + b_fc   (h lives in wave 0 registers)
    if (w == 0) {
        float part = act ? h * W_fc[u] : 0.0f;
        #pragma unroll
        for (int off = 32; off > 0; off >>= 1) part += __shfl_down(part, off);
        if (u == 0) out[b] = part + b_fc[0];
    }
}

extern "C" void kernel_launch(void* const* d_in, const int* in_sizes, int n_in,
                              void* d_out, int out_size, void* d_ws, size_t ws_size,
                              hipStream_t stream) {
    const float* x    = (const float*)d_in[0];
    const float* W_ih = (const float*)d_in[1];
    const float* W_hh = (const float*)d_in[2];
    const float* b_ih = (const float*)d_in[3];
    const float* b_hh = (const float*)d_in[4];
    const float* W_fc = (const float*)d_in[5];
    const float* b_fc = (const float*)d_in[6];
    float* out = (float*)d_out;

    const int B = in_sizes[0] / T_LEN;   // 4096
    lstm_fused<<<dim3(B), dim3(256), 0, stream>>>(x, W_ih, W_hh, b_ih, b_hh, W_fc, b_fc, out);
}